// Round 7
// baseline (170.271 us; speedup 1.0000x reference)
//
#include <hip/hip_runtime.h>

// out[b,m,f,t] = sum_c W[m,f,c] * x[b,m,c,t]
// x: [B=256][NM=5][NC=64][T=1024] f32, W: [NM=5][NF=40][NC=64] f32
// out: [B][NM][NF=40][T] f32
//
// R6 = R4 geometry + allocator pinning. R2/R4 failed because the backend
// demoted the 40-float accumulator (VGPR_Count 32/36 -> AGPR/scratch
// shuffles, VALUBusy 60-72%, 1.2-1.5 TB/s). Pin waves/EU to exactly 5
// (VGPR budget 96 >> demand ~65) so the allocator keeps acc in arch VGPRs.
// Geometry: one block per quarter t-row -> x read once, out written once,
// grid 5120 = exactly 4 generations at 5 blocks/CU (zero dispatch tail),
// 20 waves/CU for latency hiding.

#define B_  256
#define NM_ 5
#define NC_ 64
#define T_  1024
#define NF_ 40
#define QT_ 256       // t's per block
#define CCHUNK 8

__global__ __launch_bounds__(256)
__attribute__((amdgpu_waves_per_eu(5, 5)))
void trca_einsum_kernel(
    const float* __restrict__ x,
    const float* __restrict__ W,
    float* __restrict__ out)
{
    const int tile = blockIdx.x;        // 0..5119
    const int q    = tile & 3;          // quarter index within T
    const int bm   = tile >> 2;         // b*NM + m
    const int m    = bm % NM_;
    const int t0   = q * QT_ + threadIdx.x;

    const float* __restrict__ xp = x + (size_t)bm * NC_ * T_ + t0;  // stride T_ per c
    const float* __restrict__ wp = W + (size_t)m * NF_ * NC_;       // W[m,f,c]
    float* __restrict__ op = out + (size_t)bm * NF_ * T_ + t0;      // stride T_ per f

    float acc[NF_];
#pragma unroll
    for (int f = 0; f < NF_; ++f) acc[f] = 0.0f;

#pragma unroll 1
    for (int cc = 0; cc < NC_; cc += CCHUNK) {
        float xv[CCHUNK];
#pragma unroll
        for (int i = 0; i < CCHUNK; ++i) {
            xv[i] = xp[(size_t)(cc + i) * T_];
        }
#pragma unroll
        for (int i = 0; i < CCHUNK; ++i) {
#pragma unroll
            for (int f = 0; f < NF_; ++f) {
                acc[f] += wp[f * NC_ + cc + i] * xv[i];  // w: wave-uniform s_load
            }
        }
    }

    // Force accumulators into arch VGPRs (defeats AGPR demotion).
#pragma unroll
    for (int f = 0; f < NF_; ++f) asm volatile("" : "+v"(acc[f]));

#pragma unroll
    for (int f = 0; f < NF_; ++f) {
        __builtin_nontemporal_store(acc[f], op + (size_t)f * T_);
    }
}

extern "C" void kernel_launch(void* const* d_in, const int* in_sizes, int n_in,
                              void* d_out, int out_size, void* d_ws, size_t ws_size,
                              hipStream_t stream)
{
    const float* x = (const float*)d_in[0];
    const float* W = (const float*)d_in[1];
    float* out = (float*)d_out;

    const int grid = B_ * NM_ * (T_ / QT_);   // 5120 blocks
    trca_einsum_kernel<<<grid, 256, 0, stream>>>(x, W, out);
}